// Round 5
// baseline (221.062 us; speedup 1.0000x reference)
//
#include <hip/hip_runtime.h>
#include <stdint.h>

#define N_NODES 8192
#define KPAD 272
#define OUTC 384

typedef __attribute__((ext_vector_type(8))) short bhalf8;
typedef __attribute__((ext_vector_type(16))) float f32x16;
typedef __attribute__((ext_vector_type(4))) float f32x4;

__device__ inline unsigned short f2bf_rne(float f) {
    unsigned u = __builtin_bit_cast(unsigned, f);
    u += 0x7FFFu + ((u >> 16) & 1u);
    return (unsigned short)(u >> 16);
}

__device__ inline float bf2f(unsigned short u) {
    return __builtin_bit_cast(float, ((unsigned)u) << 16);
}

__device__ inline bhalf8 mk8(unsigned a, unsigned b, unsigned c, unsigned d) {
    union { unsigned u[4]; bhalf8 v; } U;
    U.u[0] = a; U.u[1] = b; U.u[2] = c; U.u[3] = d;
    return U.v;
}

__device__ inline float sigm(float s) {
    return __builtin_amdgcn_rcpf(1.f + __builtin_amdgcn_exp2f(s * -1.44269504f));
}

#define GLD_TO_LDS(gptr, lptr)                                                              \
    __builtin_amdgcn_global_load_lds((const __attribute__((address_space(1))) void*)(gptr), \
                                     (__attribute__((address_space(3))) void*)(lptr), 16, 0, 0)

// ---------------- prep: pack x (bf16, K-padded), WcatT, WrT, bcat ----------------
__global__ void k_prep(const float* __restrict__ landmarks, const float* __restrict__ features,
                       const float* __restrict__ Wi, const float* __restrict__ bi,
                       const float* __restrict__ Wj, const float* __restrict__ bj,
                       const float* __restrict__ Wk, const float* __restrict__ bk,
                       const float* __restrict__ Wr,
                       unsigned short* __restrict__ xb, unsigned short* __restrict__ WcatT,
                       unsigned short* __restrict__ WrT, float* __restrict__ bcat) {
    int idx = blockIdx.x * 256 + threadIdx.x;
    const int XB_N = N_NODES * KPAD;
    const int WC_N = OUTC * KPAD;
    const int WR_N = 256 * 128;
    if (idx < XB_N) {
        int i = idx / KPAD, kk = idx - i * KPAD;
        float v = 0.f;
        if (kk < 256) v = features[i * 256 + kk];
        else if (kk < 259) v = landmarks[i * 3 + (kk - 256)];
        xb[idx] = f2bf_rne(v);
        return;
    }
    idx -= XB_N;
    if (idx < WC_N) {
        int n = idx / KPAD, kk = idx - n * KPAD;
        int sel = n >> 7, d = n & 127;
        const float* W = (sel == 0) ? Wi : ((sel == 1) ? Wj : Wk);
        float v = 0.f;
        if (kk < 256) v = W[(kk + 3) * 128 + d];
        else if (kk < 259) v = W[(kk - 256) * 128 + d];
        WcatT[idx] = f2bf_rne(v);
        return;
    }
    idx -= WC_N;
    if (idx < WR_N) {
        int c = idx >> 7, d = idx & 127;
        WrT[idx] = f2bf_rne(Wr[d * 256 + c]);
        return;
    }
    idx -= WR_N;
    if (idx < OUTC) {
        float v = (idx < 128) ? bi[idx] : ((idx < 256) ? bj[idx - 128] : bk[idx - 256]);
        bcat[idx] = v;
    }
}

// ---------------- k1: projections, 768 blocks (3/CU): block = (i-tile 32) x (n-segment 128) ----
__global__ __launch_bounds__(256) void k_proj(const unsigned short* __restrict__ xb,
                                              const unsigned short* __restrict__ WcatT,
                                              const float* __restrict__ bcat,
                                              unsigned short* __restrict__ fi,
                                              unsigned short* __restrict__ fj,
                                              unsigned short* __restrict__ fkT) {
    const int tid = threadIdx.x;
    const int w = tid >> 6, l = tid & 63, h = l >> 5, ln = l & 31;
    const int rt = blockIdx.x / 3, nseg = blockIdx.x - rt * 3;
    const int i0 = rt * 32;
    const int n = nseg * 128 + w * 32 + ln;
    f32x16 acc = {};
#pragma unroll
    for (int s = 0; s < 17; ++s) {
        bhalf8 a = *(const bhalf8*)(xb + (size_t)(i0 + ln) * KPAD + s * 16 + h * 8);
        bhalf8 b = *(const bhalf8*)(WcatT + (size_t)n * KPAD + s * 16 + h * 8);
        acc = __builtin_amdgcn_mfma_f32_32x32x16_bf16(a, b, acc, 0, 0, 0);
    }
    const int d = n & 127;
    const float bias = bcat[n];
#pragma unroll
    for (int q = 0; q < 4; ++q) {
        int ib = i0 + 8 * q + 4 * h;
        if (nseg < 2) {
            unsigned short* dst = nseg ? fj : fi;
#pragma unroll
            for (int r = 0; r < 4; ++r)
                dst[(size_t)(ib + r) * 128 + d] = f2bf_rne(acc[4 * q + r] + bias);
        } else {
            ushort4 pk;
            pk.x = f2bf_rne(acc[4 * q + 0] + bias);
            pk.y = f2bf_rne(acc[4 * q + 1] + bias);
            pk.z = f2bf_rne(acc[4 * q + 2] + bias);
            pk.w = f2bf_rne(acc[4 * q + 3] + bias);
            *(ushort4*)(fkT + (size_t)d * N_NODES + ib) = pk;
        }
    }
}

// ---------------- k2: fused sigmoid-attention, fj register-pipelined, fi in LDS ----------------
// 256 thr / 4 waves, i=64/block, 16x 128-j tiles, 2x unrolled K-loop.
// LDS 81920 B: fi_s 16K @0 | fk0 32K @16384 | fk1 32K @49152 (exactly 2 blocks/CU).
__global__ __launch_bounds__(256, 2) void k_attn(const unsigned short* __restrict__ fi,
                                                 const unsigned short* __restrict__ fj,
                                                 const unsigned short* __restrict__ fkT,
                                                 unsigned short* __restrict__ num_part,
                                                 float* __restrict__ den_part) {
    __shared__ __align__(16) char smem[81920];
    char* fi_s = smem;
    char* fk0 = smem + 16384;
    char* fk1 = smem + 49152;
    float* bufA = (float*)(smem + 16384);     // post-loop reduce (aliases fk0)
    float* bufB = (float*)(smem + 33792);     // spans fk0/fk1 — post-loop only
    float* denb = (float*)smem;               // aliases fi_s — post-loop only

    const int tid = threadIdx.x;
    const int w = tid >> 6, l = tid & 63, h = l >> 5, ln = l & 31;
    const int jq = blockIdx.x & 3, rt = blockIdx.x >> 2;
    const int i0 = rt * 64;
    const int jbase = jq * 2048;

    const int rsub = l >> 4;
    const int cph = l & 15;

    f32x16 acc[8] = {};
    float dacc0 = 0.f, dacc1 = 0.f;

    // prologue: stage fi tile (64 rows), fk tile0 -> fk0, fj tile0 -> regs
#pragma unroll
    for (int q = 0; q < 4; ++q) {
        int r = w * 16 + q * 4 + rsub;
        int c = cph ^ (r & 15);
        GLD_TO_LDS(fi + (size_t)(i0 + r) * 128 + c * 8, fi_s + (w * 16 + q * 4) * 256);
    }
    {
        const int j00 = jbase + ((rt & 15) * 128);
#pragma unroll
        for (int q = 0; q < 8; ++q) {
            int r = w * 32 + q * 4 + rsub;
            int c = cph ^ (r & 15);
            GLD_TO_LDS(fkT + (size_t)r * N_NODES + j00 + c * 8, fk0 + (w * 32 + q * 4) * 256);
        }
    }
    bhalf8 fjA[8], fjB[8];
    {
        const int jrow = jbase + ((rt & 15) * 128) + w * 32 + ln;
#pragma unroll
        for (int s = 0; s < 8; ++s)
            fjA[s] = *(const bhalf8*)(fj + (size_t)jrow * 128 + s * 16 + h * 8);
    }

    auto compute_tile = [&](bhalf8 (&fjr)[8], char* fk_cur) {
        // S^T = fj @ fi^T ; fi B-frags from LDS
        f32x16 st0 = {}, st1 = {};
        const int rm = ln & 15;
#pragma unroll
        for (int s = 0; s < 8; ++s) {
            int c = (s * 2 + h) ^ rm;
            bhalf8 b0 = *(const bhalf8*)(fi_s + ln * 256 + c * 16);
            bhalf8 b1 = *(const bhalf8*)(fi_s + (32 + ln) * 256 + c * 16);
            st0 = __builtin_amdgcn_mfma_f32_32x32x16_bf16(fjr[s], b0, st0, 0, 0, 0);
            st1 = __builtin_amdgcn_mfma_f32_32x32x16_bf16(fjr[s], b1, st1, 0, 0, 0);
        }
        // sigmoid + pack, chunked to cap liveness
        unsigned p0[8], p1[8], x0v[8], x1v[8];
#pragma unroll
        for (int q = 0; q < 8; ++q) {
            float a0 = sigm(st0[2 * q]), b0 = sigm(st0[2 * q + 1]);
            dacc0 += a0 + b0;
            p0[q] = __builtin_amdgcn_perm(__builtin_bit_cast(unsigned, b0),
                                          __builtin_bit_cast(unsigned, a0), 0x07060302u);
        }
#pragma unroll
        for (int q = 0; q < 8; ++q) {
            float a1 = sigm(st1[2 * q]), b1 = sigm(st1[2 * q + 1]);
            dacc1 += a1 + b1;
            p1[q] = __builtin_amdgcn_perm(__builtin_bit_cast(unsigned, b1),
                                          __builtin_bit_cast(unsigned, a1), 0x07060302u);
        }
#pragma unroll
        for (int q = 0; q < 8; ++q) {
            x0v[q] = (unsigned)__shfl_xor((int)p0[q], 32, 64);
            x1v[q] = (unsigned)__shfl_xor((int)p1[q], 32, 64);
        }
        bhalf8 fb[2][2];
        if (h == 0) {
            fb[0][0] = mk8(p0[0], p0[1], x0v[0], x0v[1]);
            fb[0][1] = mk8(p0[4], p0[5], x0v[4], x0v[5]);
            fb[1][0] = mk8(p1[0], p1[1], x1v[0], x1v[1]);
            fb[1][1] = mk8(p1[4], p1[5], x1v[4], x1v[5]);
        } else {
            fb[0][0] = mk8(x0v[2], x0v[3], p0[2], p0[3]);
            fb[0][1] = mk8(x0v[6], x0v[7], p0[6], p0[7]);
            fb[1][0] = mk8(x1v[2], x1v[3], p1[2], p1[3]);
            fb[1][1] = mk8(x1v[6], x1v[7], p1[6], p1[7]);
        }
        // PV: numT[d][i] += fkT[d][j] * P^T[j][i]
#pragma unroll
        for (int m4 = 0; m4 < 4; ++m4) {
#pragma unroll
            for (int s2 = 0; s2 < 2; ++s2) {
                int row = m4 * 32 + ln;
                int c = (w * 4 + s2 * 2 + h) ^ (row & 15);
                bhalf8 af = *(const bhalf8*)(fk_cur + row * 256 + c * 16);
                acc[m4 * 2 + 0] = __builtin_amdgcn_mfma_f32_32x32x16_bf16(af, fb[0][s2], acc[m4 * 2 + 0], 0, 0, 0);
                acc[m4 * 2 + 1] = __builtin_amdgcn_mfma_f32_32x32x16_bf16(af, fb[1][s2], acc[m4 * 2 + 1], 0, 0, 0);
            }
        }
    };

    auto stage_fk = [&](int t, char* dst) {
        const int j0 = jbase + (((t + rt) & 15) * 128);
#pragma unroll
        for (int q = 0; q < 8; ++q) {
            int r = w * 32 + q * 4 + rsub;
            int c = cph ^ (r & 15);
            GLD_TO_LDS(fkT + (size_t)r * N_NODES + j0 + c * 8, dst + (w * 32 + q * 4) * 256);
        }
    };
    auto load_fj = [&](int t, bhalf8 (&dst)[8]) {
        const int jrow = jbase + (((t + rt) & 15) * 128) + w * 32 + ln;
#pragma unroll
        for (int s = 0; s < 8; ++s)
            dst[s] = *(const bhalf8*)(fj + (size_t)jrow * 128 + s * 16 + h * 8);
    };

    for (int tr = 0; tr < 8; ++tr) {
        const int t0 = 2 * tr;
        __syncthreads();                 // fk0(t0) + fjB-from-prev landed
        stage_fk(t0 + 1, fk1);           // in flight across tile-t0 compute
        load_fj(t0 + 1, fjB);
        compute_tile(fjA, fk0);
        __syncthreads();                 // fk1(t0+1) landed
        if (tr < 7) {
            stage_fk(t0 + 2, fk0);
            load_fj(t0 + 2, fjA);
        }
        compute_tile(fjB, fk1);
    }

    __syncthreads();    // all waves done with fi_s/fk — LDS free for reduce aliases

    // denom: fold lane l <-> l^32, stash per-wave into denb (aliases fi_s)
    {
        float o0 = __shfl_xor(dacc0, 32, 64);
        float o1 = __shfl_xor(dacc1, 32, 64);
        dacc0 += o0; dacc1 += o1;
    }
    if (h == 0) {
        denb[w * 64 + ln] = dacc0;
        denb[w * 64 + 32 + ln] = dacc1;
    }

    // cross-wave num reduce in two d-halves
#pragma unroll
    for (int half = 0; half < 2; ++half) {
        __syncthreads();
        if (w < 2) {
            float* buf = w ? bufB : bufA;
#pragma unroll
            for (int m2 = 0; m2 < 2; ++m2) {
                int m4 = half * 2 + m2;
#pragma unroll
                for (int nt = 0; nt < 2; ++nt) {
                    int iloc = nt * 32 + ln;
#pragma unroll
                    for (int q = 0; q < 4; ++q) {
                        int d = m2 * 32 + 8 * q + 4 * h;
                        f32x4 v = {acc[m4 * 2 + nt][4 * q + 0], acc[m4 * 2 + nt][4 * q + 1],
                                   acc[m4 * 2 + nt][4 * q + 2], acc[m4 * 2 + nt][4 * q + 3]};
                        *(f32x4*)(buf + iloc * 68 + d) = v;
                    }
                }
            }
        }
        __syncthreads();
        if (w >= 2) {
            float* buf = (w == 3) ? bufB : bufA;
#pragma unroll
            for (int m2 = 0; m2 < 2; ++m2) {
                int m4 = half * 2 + m2;
#pragma unroll
                for (int nt = 0; nt < 2; ++nt) {
                    int iloc = nt * 32 + ln;
#pragma unroll
                    for (int q = 0; q < 4; ++q) {
                        int d = m2 * 32 + 8 * q + 4 * h;
                        f32x4 old = *(f32x4*)(buf + iloc * 68 + d);
                        f32x4 v = {acc[m4 * 2 + nt][4 * q + 0], acc[m4 * 2 + nt][4 * q + 1],
                                   acc[m4 * 2 + nt][4 * q + 2], acc[m4 * 2 + nt][4 * q + 3]};
                        *(f32x4*)(buf + iloc * 68 + d) = old + v;
                    }
                }
            }
        }
        __syncthreads();
#pragma unroll
        for (int e = 0; e < 4; ++e) {
            int v = e * 256 + tid;
            int iloc = v >> 4;
            int d4 = (v & 15) * 4;
            f32x4 s = *(f32x4*)(bufA + iloc * 68 + d4) + *(f32x4*)(bufB + iloc * 68 + d4);
            ushort4 pk;
            pk.x = f2bf_rne(s.x); pk.y = f2bf_rne(s.y);
            pk.z = f2bf_rne(s.z); pk.w = f2bf_rne(s.w);
            *(ushort4*)(num_part + (size_t)(jq * N_NODES + i0 + iloc) * 128 + half * 64 + d4) = pk;
        }
    }
    __syncthreads();
    if (tid < 64) {
        den_part[(size_t)jq * N_NODES + i0 + tid] =
            denb[tid] + denb[64 + tid] + denb[128 + tid] + denb[192 + tid];
    }
}

// ---------------- k3: combine partials -> t, then out = t @ Wr + br + features ----------------
// 512 blocks: (i-tile 32) x (output-col half 128). 2/CU.
__global__ __launch_bounds__(256) void k_out(const unsigned short* __restrict__ num_part,
                                             const float* __restrict__ den_part,
                                             const unsigned short* __restrict__ WrT,
                                             const float* __restrict__ br,
                                             const float* __restrict__ features,
                                             float* __restrict__ out) {
    __shared__ __align__(16) char smem[40960];                 // WrT-half 32 KB + t_s 8 KB
    unsigned short* t_s = (unsigned short*)(smem + 32768);     // [32 i][128 d] swizzled
    const int tid = threadIdx.x, w = tid >> 6, l = tid & 63, h = l >> 5, ln = l & 31;
    const int i0 = (blockIdx.x >> 1) * 32;
    const int ch = blockIdx.x & 1;
    {
        int rsub = l >> 4, cph = l & 15;
#pragma unroll
        for (int q = 0; q < 8; ++q) {
            int r = w * 32 + q * 4 + rsub;              // local row 0..127
            int c = cph ^ (r & 15);
            GLD_TO_LDS(WrT + (size_t)(ch * 128 + r) * 128 + c * 8, smem + (w * 32 + q * 4) * 256);
        }
    }
    // combine 4 j-partials -> t tile in LDS (512 ushort8 groups, 2 per thread)
#pragma unroll
    for (int e = 0; e < 2; ++e) {
        int v = e * 256 + tid;
        int r = v >> 4, c8 = v & 15;
        float s[8] = {};
        float den = 0.f;
#pragma unroll
        for (int q = 0; q < 4; ++q) {
            const unsigned short* p = num_part + (size_t)(q * N_NODES + i0 + r) * 128 + c8 * 8;
            union { uint4 u; unsigned short us[8]; } U;
            U.u = *(const uint4*)p;
#pragma unroll
            for (int z = 0; z < 8; ++z) s[z] += bf2f(U.us[z]);
            den += den_part[(size_t)q * N_NODES + i0 + r];
        }
        float inv = 1.0f / den;
        union { ushort4 a[2]; uint4 u; } P;
#pragma unroll
        for (int z = 0; z < 8; ++z) ((unsigned short*)&P)[z] = f2bf_rne(s[z] * inv);
        int pc = c8 ^ (r & 15);
        *(uint4*)((char*)t_s + r * 256 + pc * 16) = P.u;
    }
    __syncthreads();
    f32x16 acc = {};
#pragma unroll
    for (int s = 0; s < 8; ++s) {
        int ca = (s * 2 + h) ^ (ln & 15);
        bhalf8 af = *(const bhalf8*)((char*)t_s + ln * 256 + ca * 16);
        int row = w * 32 + ln;
        int c = (s * 2 + h) ^ (row & 15);
        bhalf8 bf = *(const bhalf8*)(smem + row * 256 + c * 16);
        acc = __builtin_amdgcn_mfma_f32_32x32x16_bf16(af, bf, acc, 0, 0, 0);
    }
    {
        int cc = ch * 128 + w * 32 + ln;
        float bias = br[cc];
#pragma unroll
        for (int q = 0; q < 4; ++q) {
#pragma unroll
            for (int r = 0; r < 4; ++r) {
                int i = i0 + 8 * q + 4 * h + r;
                out[(size_t)i * 256 + cc] = acc[4 * q + r] + bias + features[(size_t)i * 256 + cc];
            }
        }
    }
}

extern "C" void kernel_launch(void* const* d_in, const int* in_sizes, int n_in,
                              void* d_out, int out_size, void* d_ws, size_t ws_size,
                              hipStream_t stream) {
    const float* landmarks = (const float*)d_in[0];
    const float* features  = (const float*)d_in[1];
    const float* Wi = (const float*)d_in[2];
    const float* bi = (const float*)d_in[3];
    const float* Wj = (const float*)d_in[4];
    const float* bj = (const float*)d_in[5];
    const float* Wk = (const float*)d_in[6];
    const float* bk = (const float*)d_in[7];
    const float* Wr = (const float*)d_in[8];
    const float* br = (const float*)d_in[9];

    char* ws = (char*)d_ws;
    unsigned short* xb      = (unsigned short*)(ws + 0);         // 8192x272 bf16
    unsigned short* WcatT   = (unsigned short*)(ws + 4456448);   // 384x272 bf16
    unsigned short* WrT     = (unsigned short*)(ws + 4665344);   // 256x128 bf16
    float*          bcat    = (float*)(ws + 4730880);            // 384 f32
    unsigned short* fi      = (unsigned short*)(ws + 4732416);   // 8192x128 bf16
    unsigned short* fjp     = (unsigned short*)(ws + 6829568);   // 8192x128 bf16
    unsigned short* fkT     = (unsigned short*)(ws + 8926720);   // 128x8192 bf16
    unsigned short* num_part= (unsigned short*)(ws + 11023872);  // 4x8192x128 bf16
    float*          den_part= (float*)(ws + 19412480);           // 4x8192 f32

    float* out = (float*)d_out;

    hipLaunchKernelGGL(k_prep, dim3(9242), dim3(256), 0, stream,
                       landmarks, features, Wi, bi, Wj, bj, Wk, bk, Wr, xb, WcatT, WrT, bcat);
    hipLaunchKernelGGL(k_proj, dim3(768), dim3(256), 0, stream, xb, WcatT, bcat, fi, fjp, fkT);
    hipLaunchKernelGGL(k_attn, dim3(512), dim3(256), 0, stream, fi, fjp, fkT, num_part, den_part);
    hipLaunchKernelGGL(k_out, dim3(512), dim3(256), 0, stream, num_part, den_part, WrT, br, features, out);
}

// Round 6
// 206.125 us; speedup vs baseline: 1.0725x; 1.0725x over previous
//
#include <hip/hip_runtime.h>
#include <stdint.h>

#define N_NODES 8192
#define KPAD 272
#define OUTC 384

typedef __attribute__((ext_vector_type(8))) short bhalf8;
typedef __attribute__((ext_vector_type(16))) float f32x16;

__device__ inline unsigned short f2bf_rne(float f) {
    unsigned u = __builtin_bit_cast(unsigned, f);
    u += 0x7FFFu + ((u >> 16) & 1u);
    return (unsigned short)(u >> 16);
}

__device__ inline float bf2f(unsigned short u) {
    return __builtin_bit_cast(float, ((unsigned)u) << 16);
}

__device__ inline float sigm(float s) {
    return __builtin_amdgcn_rcpf(1.f + __builtin_amdgcn_exp2f(s * -1.44269504f));
}

#define GLD_TO_LDS(gptr, lptr)                                                              \
    __builtin_amdgcn_global_load_lds((const __attribute__((address_space(1))) void*)(gptr), \
                                     (__attribute__((address_space(3))) void*)(lptr), 16, 0, 0)

// ---------------- prep: pack x (bf16, K-padded), WcatT, WrT, bcat ----------------
__global__ void k_prep(const float* __restrict__ landmarks, const float* __restrict__ features,
                       const float* __restrict__ Wi, const float* __restrict__ bi,
                       const float* __restrict__ Wj, const float* __restrict__ bj,
                       const float* __restrict__ Wk, const float* __restrict__ bk,
                       const float* __restrict__ Wr,
                       unsigned short* __restrict__ xb, unsigned short* __restrict__ WcatT,
                       unsigned short* __restrict__ WrT, float* __restrict__ bcat) {
    int idx = blockIdx.x * 256 + threadIdx.x;
    const int XB_N = N_NODES * KPAD;
    const int WC_N = OUTC * KPAD;
    const int WR_N = 256 * 128;
    if (idx < XB_N) {
        int i = idx / KPAD, kk = idx - i * KPAD;
        float v = 0.f;
        if (kk < 256) v = features[i * 256 + kk];
        else if (kk < 259) v = landmarks[i * 3 + (kk - 256)];
        xb[idx] = f2bf_rne(v);
        return;
    }
    idx -= XB_N;
    if (idx < WC_N) {
        int n = idx / KPAD, kk = idx - n * KPAD;
        int sel = n >> 7, d = n & 127;
        const float* W = (sel == 0) ? Wi : ((sel == 1) ? Wj : Wk);
        float v = 0.f;
        if (kk < 256) v = W[(kk + 3) * 128 + d];
        else if (kk < 259) v = W[(kk - 256) * 128 + d];
        WcatT[idx] = f2bf_rne(v);
        return;
    }
    idx -= WC_N;
    if (idx < WR_N) {
        int c = idx >> 7, d = idx & 127;
        WrT[idx] = f2bf_rne(Wr[d * 256 + c]);
        return;
    }
    idx -= WR_N;
    if (idx < OUTC) {
        float v = (idx < 128) ? bi[idx] : ((idx < 256) ? bj[idx - 128] : bk[idx - 256]);
        bcat[idx] = v;
    }
}

// ---------------- k1: projections, 768 blocks: block = (i-tile 32) x (n-segment 128) ----------
__global__ __launch_bounds__(256) void k_proj(const unsigned short* __restrict__ xb,
                                              const unsigned short* __restrict__ WcatT,
                                              const float* __restrict__ bcat,
                                              unsigned short* __restrict__ fi,
                                              unsigned short* __restrict__ fj,
                                              unsigned short* __restrict__ fkT) {
    const int tid = threadIdx.x;
    const int w = tid >> 6, l = tid & 63, h = l >> 5, ln = l & 31;
    const int rt = blockIdx.x / 3, nseg = blockIdx.x - rt * 3;
    const int i0 = rt * 32;
    const int n = nseg * 128 + w * 32 + ln;
    f32x16 acc = {};
#pragma unroll
    for (int s = 0; s < 17; ++s) {
        bhalf8 a = *(const bhalf8*)(xb + (size_t)(i0 + ln) * KPAD + s * 16 + h * 8);
        bhalf8 b = *(const bhalf8*)(WcatT + (size_t)n * KPAD + s * 16 + h * 8);
        acc = __builtin_amdgcn_mfma_f32_32x32x16_bf16(a, b, acc, 0, 0, 0);
    }
    const int d = n & 127;
    const float bias = bcat[n];
#pragma unroll
    for (int q = 0; q < 4; ++q) {
        int ib = i0 + 8 * q + 4 * h;
        if (nseg < 2) {
            unsigned short* dst = nseg ? fj : fi;
#pragma unroll
            for (int r = 0; r < 4; ++r)
                dst[(size_t)(ib + r) * 128 + d] = f2bf_rne(acc[4 * q + r] + bias);
        } else {
            ushort4 pk;
            pk.x = f2bf_rne(acc[4 * q + 0] + bias);
            pk.y = f2bf_rne(acc[4 * q + 1] + bias);
            pk.z = f2bf_rne(acc[4 * q + 2] + bias);
            pk.w = f2bf_rne(acc[4 * q + 3] + bias);
            *(ushort4*)(fkT + (size_t)d * N_NODES + ib) = pk;
        }
    }
}

// ---------------- k2: fused sigmoid-attention, P-through-LDS, d-split waves ----------------
// 256 thr / 4 waves, i-tile 64, j-tile 64, 16 tiles per j-eighth. Grid 1024 = 128 rt x 8 jq.
// Wave roles: phase A (S+sigmoid+P-write): (js = w&1 j-strip, ih = w>>1 i-half), st = 1 tile.
//             phase B (PV): d-quarter dt = w, acc = 2 tiles (32 AGPR). No cross-wave reduce.
// LDS 24.5 KB: fk_s [128 d][64 j] 16K | p_s [64 i][64 j] 8K | denb 0.5K. 3 waves/SIMD target.
__global__ __launch_bounds__(256, 3) void k_attn(const unsigned short* __restrict__ fi,
                                                 const unsigned short* __restrict__ fj,
                                                 const unsigned short* __restrict__ fkT,
                                                 unsigned short* __restrict__ num_part,
                                                 float* __restrict__ den_part) {
    __shared__ __align__(16) char smem[25088];
    char* fk_s = smem;                       // [128 d][8 chunks], pitch 128 B, chunk ^ (row&7)
    char* p_s = smem + 16384;                // [64 i][8 chunks], pitch 128 B, chunk ^ (row&7)
    float* denb = (float*)(smem + 24576);    // [4][32]

    const int tid = threadIdx.x;
    const int w = tid >> 6, l = tid & 63, h = l >> 5, ln = l & 31;
    const int js = w & 1, ih = w >> 1;       // phase-A role
    const int dt = w;                        // phase-B role
    const int jq = blockIdx.x & 7, rt = blockIdx.x >> 3;   // jq low bits -> XCD-pinned eighth
    const int i0 = rt * 64;
    const int jbase = jq * 1024;

    // fi B-fragments for this wave's 32-i half (32 VGPRs)
    bhalf8 bfi[8];
#pragma unroll
    for (int s = 0; s < 8; ++s)
        bfi[s] = *(const bhalf8*)(fi + (size_t)(i0 + ih * 32 + ln) * 128 + s * 16 + h * 8);

    f32x16 acc0 = {}, acc1 = {};   // PV acc: d-quarter dt x i-tiles {0,1}
    float dacc = 0.f;

    for (int mt = 0; mt < 16; ++mt) {
        const int j0 = jbase + (((mt + rt) & 15) << 6);   // stagger across blocks
        __syncthreads();   // α: previous tile's p_s/fk_s fully consumed
        // stage fk tile [128 d][64 j] (4 GLD/wave), lands during phase A
#pragma unroll
        for (int q = 0; q < 4; ++q) {
            int idx = (w * 4 + q) * 64 + l;
            int row = idx >> 3;
            int cj = (l & 7) ^ (row & 7);
            GLD_TO_LDS(fkT + (size_t)row * N_NODES + j0 + cj * 8, fk_s + idx * 16);
        }
        // phase A: st = S^T strip [32 j (js)][32 i (ih)]; fj A-frags direct from global
        f32x16 st = {};
        const int jrow = j0 + js * 32 + ln;
#pragma unroll
        for (int s = 0; s < 8; ++s) {
            bhalf8 af = *(const bhalf8*)(fj + (size_t)jrow * 128 + s * 16 + h * 8);
            st = __builtin_amdgcn_mfma_f32_32x32x16_bf16(af, bfi[s], st, 0, 0, 0);
        }
        // sigmoid + pack consecutive-j pairs to bf16, accumulate denom
        unsigned p[8];
#pragma unroll
        for (int q = 0; q < 8; ++q) {
            float a = sigm(st[2 * q]);
            float b = sigm(st[2 * q + 1]);
            dacc += a + b;
            p[q] = __builtin_amdgcn_perm(__builtin_bit_cast(unsigned, b),
                                         __builtin_bit_cast(unsigned, a), 0x07060302u);
        }
        // write P^T to p_s in [i][j] layout (C-layout cols are i=ln; rows j per reg formula)
        {
            const int prow = ih * 32 + ln;
#pragma unroll
            for (int qp = 0; qp < 4; ++qp) {
                int c = js * 4 + qp;                       // j-chunk (8 j per 16 B)
                int pch = c ^ (prow & 7);
                uint2 v;
                v.x = p[2 * qp]; v.y = p[2 * qp + 1];      // j = 8*qp + 4*h + {0..3}
                *(uint2*)(p_s + prow * 128 + pch * 16 + h * 8) = v;
            }
        }
        __syncthreads();   // β: p_s(t) visible; fk staging drained
        // phase B: PV for d-quarter dt: num[d][i] += fk[d][j] * P^T[j][i]
#pragma unroll
        for (int kt = 0; kt < 4; ++kt) {
            const int arow = dt * 32 + ln;
            const int ac = (kt * 2 + h) ^ (arow & 7);
            bhalf8 af = *(const bhalf8*)(fk_s + arow * 128 + ac * 16);
            const int bc = (kt * 2 + h) ^ (ln & 7);
            bhalf8 bf0 = *(const bhalf8*)(p_s + ln * 128 + bc * 16);
            acc0 = __builtin_amdgcn_mfma_f32_32x32x16_bf16(af, bf0, acc0, 0, 0, 0);
            bhalf8 bf1 = *(const bhalf8*)(p_s + (32 + ln) * 128 + bc * 16);
            acc1 = __builtin_amdgcn_mfma_f32_32x32x16_bf16(af, bf1, acc1, 0, 0, 0);
        }
    }

    // denom: fold h (lane ^ 32), stash per wave
    dacc += __shfl_xor(dacc, 32, 64);
    if (h == 0) denb[w * 32 + ln] = dacc;

    // num: wave dt owns d-rows [dt*32, dt*32+32) for i-rows [i0, i0+64) — direct store
#pragma unroll
    for (int it = 0; it < 2; ++it) {
        const f32x16& a = it ? acc1 : acc0;
        size_t base = ((size_t)jq * N_NODES + i0 + it * 32 + ln) * 128 + dt * 32 + 4 * h;
#pragma unroll
        for (int g4 = 0; g4 < 4; ++g4) {
            ushort4 pk;
            pk.x = f2bf_rne(a[4 * g4 + 0]);
            pk.y = f2bf_rne(a[4 * g4 + 1]);
            pk.z = f2bf_rne(a[4 * g4 + 2]);
            pk.w = f2bf_rne(a[4 * g4 + 3]);
            *(ushort4*)(num_part + base + 8 * g4) = pk;
        }
    }
    __syncthreads();
    if (tid < 64) {
        int ihh = tid >> 5, t = tid & 31;
        den_part[(size_t)jq * N_NODES + i0 + tid] =
            denb[(2 * ihh) * 32 + t] + denb[(2 * ihh + 1) * 32 + t];
    }
}

// ---------------- k3: combine 8 partials -> t, then out = t @ Wr + br + features ----------------
// 512 blocks: (i-tile 32) x (output-col half 128).
__global__ __launch_bounds__(256) void k_out(const unsigned short* __restrict__ num_part,
                                             const float* __restrict__ den_part,
                                             const unsigned short* __restrict__ WrT,
                                             const float* __restrict__ br,
                                             const float* __restrict__ features,
                                             float* __restrict__ out) {
    __shared__ __align__(16) char smem[40960];                 // WrT-half 32 KB + t_s 8 KB
    unsigned short* t_s = (unsigned short*)(smem + 32768);     // [32 i][128 d] swizzled
    const int tid = threadIdx.x, w = tid >> 6, l = tid & 63, h = l >> 5, ln = l & 31;
    const int i0 = (blockIdx.x >> 1) * 32;
    const int ch = blockIdx.x & 1;
    {
        int rsub = l >> 4, cph = l & 15;
#pragma unroll
        for (int q = 0; q < 8; ++q) {
            int r = w * 32 + q * 4 + rsub;              // local row 0..127
            int c = cph ^ (r & 15);
            GLD_TO_LDS(WrT + (size_t)(ch * 128 + r) * 128 + c * 8, smem + (w * 32 + q * 4) * 256);
        }
    }
    // combine 8 j-partials -> t tile in LDS (512 ushort8 groups, 2 per thread)
#pragma unroll
    for (int e = 0; e < 2; ++e) {
        int v = e * 256 + tid;
        int r = v >> 4, c8 = v & 15;
        float s[8] = {};
        float den = 0.f;
#pragma unroll
        for (int q = 0; q < 8; ++q) {
            const unsigned short* p = num_part + (size_t)(q * N_NODES + i0 + r) * 128 + c8 * 8;
            union { uint4 u; unsigned short us[8]; } U;
            U.u = *(const uint4*)p;
#pragma unroll
            for (int z = 0; z < 8; ++z) s[z] += bf2f(U.us[z]);
            den += den_part[(size_t)q * N_NODES + i0 + r];
        }
        float inv = 1.0f / den;
        union { ushort4 a[2]; uint4 u; } P;
#pragma unroll
        for (int z = 0; z < 8; ++z) ((unsigned short*)&P)[z] = f2bf_rne(s[z] * inv);
        int pc = c8 ^ (r & 15);
        *(uint4*)((char*)t_s + r * 256 + pc * 16) = P.u;
    }
    __syncthreads();
    f32x16 acc = {};
#pragma unroll
    for (int s = 0; s < 8; ++s) {
        int ca = (s * 2 + h) ^ (ln & 15);
        bhalf8 af = *(const bhalf8*)((char*)t_s + ln * 256 + ca * 16);
        int row = w * 32 + ln;
        int c = (s * 2 + h) ^ (row & 15);
        bhalf8 bf = *(const bhalf8*)(smem + row * 256 + c * 16);
        acc = __builtin_amdgcn_mfma_f32_32x32x16_bf16(af, bf, acc, 0, 0, 0);
    }
    {
        int cc = ch * 128 + w * 32 + ln;
        float bias = br[cc];
#pragma unroll
        for (int q = 0; q < 4; ++q) {
#pragma unroll
            for (int r = 0; r < 4; ++r) {
                int i = i0 + 8 * q + 4 * h + r;
                out[(size_t)i * 256 + cc] = acc[4 * q + r] + bias + features[(size_t)i * 256 + cc];
            }
        }
    }
}

extern "C" void kernel_launch(void* const* d_in, const int* in_sizes, int n_in,
                              void* d_out, int out_size, void* d_ws, size_t ws_size,
                              hipStream_t stream) {
    const float* landmarks = (const float*)d_in[0];
    const float* features  = (const float*)d_in[1];
    const float* Wi = (const float*)d_in[2];
    const float* bi = (const float*)d_in[3];
    const float* Wj = (const float*)d_in[4];
    const float* bj = (const float*)d_in[5];
    const float* Wk = (const float*)d_in[6];
    const float* bk = (const float*)d_in[7];
    const float* Wr = (const float*)d_in[8];
    const float* br = (const float*)d_in[9];

    char* ws = (char*)d_ws;
    unsigned short* xb      = (unsigned short*)(ws + 0);         // 8192x272 bf16
    unsigned short* WcatT   = (unsigned short*)(ws + 4456448);   // 384x272 bf16
    unsigned short* WrT     = (unsigned short*)(ws + 4665344);   // 256x128 bf16
    float*          bcat    = (float*)(ws + 4730880);            // 384 f32
    unsigned short* fi      = (unsigned short*)(ws + 4732416);   // 8192x128 bf16
    unsigned short* fjp     = (unsigned short*)(ws + 6829568);   // 8192x128 bf16
    unsigned short* fkT     = (unsigned short*)(ws + 8926720);   // 128x8192 bf16
    unsigned short* num_part= (unsigned short*)(ws + 11023872);  // 8x8192x128 bf16
    float*          den_part= (float*)(ws + 27801088);           // 8x8192 f32

    float* out = (float*)d_out;

    hipLaunchKernelGGL(k_prep, dim3(9242), dim3(256), 0, stream,
                       landmarks, features, Wi, bi, Wj, bj, Wk, bk, Wr, xb, WcatT, WrT, bcat);
    hipLaunchKernelGGL(k_proj, dim3(768), dim3(256), 0, stream, xb, WcatT, bcat, fi, fjp, fkT);
    hipLaunchKernelGGL(k_attn, dim3(1024), dim3(256), 0, stream, fi, fjp, fkT, num_part, den_part);
    hipLaunchKernelGGL(k_out, dim3(512), dim3(256), 0, stream, num_part, den_part, WrT, br, features, out);
}